// Round 4
// baseline (143.827 us; speedup 1.0000x reference)
//
#include <hip/hip_runtime.h>

#define BATCH 16384
#define LATENT 128
#define HIDDEN 64
#define INDIM 100
#define KPAD 128

typedef short shortx8 __attribute__((ext_vector_type(8)));
typedef float floatx4 __attribute__((ext_vector_type(4)));

__device__ __forceinline__ unsigned bfbits(float f) {
    union { float f; unsigned u; } v; v.f = f;
    return (v.u + 0x7FFF + ((v.u >> 16) & 1)) >> 16;   // RNE, inputs finite
}

#if __has_builtin(__builtin_amdgcn_rcpf)
#define RCPF(x) __builtin_amdgcn_rcpf(x)
#else
#define RCPF(x) (1.0f / (x))
#endif

// Sum across each 16-lane DPP row, full sum lands in EVERY lane (row_ror: no
// boundary loss, direction-proof — verified round 3).
#define DPP_REDUCE16(v) do {                                                              \
    v += __int_as_float(__builtin_amdgcn_update_dpp(0, __float_as_int(v), 0x128, 0xF, 0xF, true)); \
    v += __int_as_float(__builtin_amdgcn_update_dpp(0, __float_as_int(v), 0x124, 0xF, 0xF, true)); \
    v += __int_as_float(__builtin_amdgcn_update_dpp(0, __float_as_int(v), 0x122, 0xF, 0xF, true)); \
    v += __int_as_float(__builtin_amdgcn_update_dpp(0, __float_as_int(v), 0x121, 0xF, 0xF, true)); \
} while (0)

// ---------------------------------------------------------------------------
// prep: fp32 row-major -> bf16 fragment-major, via LDS transpose.
// Blocks 0..255: u rows (64 rows each, bias col k=100 := 1.0).
// Blocks 256..383: W1 rows (lat,h) (64 rows = 1 latent each, k=100 := b1).
// Phase 1: coalesced float2 reads -> packed bf16 ds_write_b32 into [64][136].
// Phase 2: conflict-free ds_read_b128 fragments -> coalesced 16B global writes.
// Layout written is byte-identical to round-3's proven uf/wf layouts.
// ---------------------------------------------------------------------------
__global__ __launch_bounds__(256) void prep_transpose(const float* __restrict__ u,
                                                      const float* __restrict__ W1,
                                                      const float* __restrict__ b1,
                                                      shortx8* __restrict__ uf,
                                                      shortx8* __restrict__ wf) {
    __shared__ short lds[64 * 136];
    int tid = threadIdx.x;
    int bx = blockIdx.x;
    bool isW = (bx >= 256);
    int row0 = isW ? (bx - 256) * 64 : bx * 64;          // global row (u) or wrow (W)
    const float* src = isW ? W1 : u;

    // Phase 1: fill LDS [64 rows][128 k padded, stride 136]
#pragma unroll
    for (int it = 0; it < 16; it++) {
        int p = it * 256 + tid;            // pair index over 64 rows x 64 pairs
        int rl = p >> 6;                   // local row
        int kp = (p & 63) * 2;             // k of pair
        int grow = row0 + rl;
        float f0, f1;
        if (kp < 100) {                    // kp even -> kp+1 <= 99
            const float2 t = *(const float2*)(src + grow * INDIM + kp);
            f0 = t.x; f1 = t.y;
        } else {
            f0 = 0.0f; f1 = 0.0f;
            if (kp == 100) f0 = isW ? b1[grow] : 1.0f;
        }
        *(unsigned*)(&lds[rl * 136 + kp]) = bfbits(f0) | (bfbits(f1) << 16);
    }
    __syncthreads();

    // Phase 2: assemble fragment chunks. chunk = ((row0/16 + gl)*4 + kt)*64 + lane,
    // value j = LDS[gl*16 + (lane&15)][kt*32 + (lane>>4)*8 + j].
    shortx8* dst = isW ? wf : uf;
    int Gbase = (row0 >> 4);               // = bx*4 (u)  or  (bw*4 since lat=bw) (W)
#pragma unroll
    for (int it = 0; it < 4; it++) {
        int idx = it * 256 + tid;
        int lane = idx & 63;
        int kt = (idx >> 6) & 3;
        int gl = idx >> 8;
        int rl = gl * 16 + (lane & 15);
        int kb = kt * 32 + ((lane >> 4) << 3);
        shortx8 v = *(const shortx8*)(&lds[rl * 136 + kb]);   // 272B row stride: 2-way banks (free)
        dst[((size_t)(Gbase + gl) * 4 + kt) * 64 + lane] = v; // coalesced 1KB/wave
    }
}

// ---------------------------------------------------------------------------
// main fused kernel. grid (64, 32), 256 thr = 4 waves.
// wave: 64 rows (gi=0..3 row-groups g0..g0+3) x 4 latents (li).
// Epilogue: tanh via exact [5/4] Pade x(945+105y+y^2)/(945+420y+15y^2),
// 4 fractions per (gi,r) combined over a common denominator -> ONE v_rcp per
// 4 tanh, everything else full-rate FMA (round-3 VALUBusy showed the two
// transcendentals per tanh were the binding pipe at ~34us).
// ---------------------------------------------------------------------------
__global__ __launch_bounds__(256, 2) void branch_mlp(const shortx8* __restrict__ uf,
                                                     const shortx8* __restrict__ wf,
                                                     const float* __restrict__ W2,
                                                     const float* __restrict__ b2,
                                                     float* __restrict__ out) {
    int tid = threadIdx.x;
    int lane = tid & 63;
    int w = tid >> 6;
    int bx = blockIdx.x;
    int by = blockIdx.y;
    int g0 = bx * 16 + w * 4;
    int q = lane >> 4;
    int col = lane & 15;

    // A fragments: 64 rows x K=128, register-resident across all 4 latents (64 VGPRs)
    shortx8 a[4][4];
    const shortx8* ua = uf + (size_t)g0 * 4 * 64 + lane;
#pragma unroll
    for (int gi = 0; gi < 4; gi++)
#pragma unroll
        for (int kt = 0; kt < 4; kt++)
            a[gi][kt] = ua[(gi * 4 + kt) * 64];

#pragma unroll
    for (int li = 0; li < 4; li++) {
        int lat = by * 4 + li;
        const shortx8* wb = wf + (size_t)lat * 16 * 64 + lane;

        float w2v[4];
#pragma unroll
        for (int nt = 0; nt < 4; nt++) w2v[nt] = W2[lat * HIDDEN + nt * 16 + col];
        float b2v = b2[lat];

        shortx8 bfr[4][4];
#pragma unroll
        for (int nt = 0; nt < 4; nt++)
#pragma unroll
            for (int kt = 0; kt < 4; kt++)
                bfr[nt][kt] = wb[(nt * 4 + kt) * 64];

        floatx4 acc[4][4] = {};   // [gi][nt]
#pragma unroll
        for (int kt = 0; kt < 4; kt++)
#pragma unroll
            for (int nt = 0; nt < 4; nt++)
#pragma unroll
                for (int gi = 0; gi < 4; gi++)
                    acc[gi][nt] = __builtin_amdgcn_mfma_f32_16x16x32_bf16(a[gi][kt], bfr[nt][kt], acc[gi][nt], 0, 0, 0);

#pragma unroll
        for (int gi = 0; gi < 4; gi++) {
            float pr[4];
#pragma unroll
            for (int r = 0; r < 4; r++) {
                float n[4], d[4];
#pragma unroll
                for (int nt = 0; nt < 4; nt++) {
                    float x = acc[gi][nt][r];
                    float y = x * x;
                    n[nt] = x * fmaf(y + 105.0f, y, 945.0f);          // x(y^2+105y+945)
                    d[nt] = fmaf(fmaf(15.0f, y, 420.0f), y, 945.0f);  // 15y^2+420y+945
                }
                float d01 = d[0] * d[1], d23 = d[2] * d[3];
                float m0 = n[0] * d[1], m1 = n[1] * d[0];
                float m2 = n[2] * d[3], m3 = n[3] * d[2];
                float s01 = fmaf(w2v[1], m1, w2v[0] * m0);
                float s23 = fmaf(w2v[3], m3, w2v[2] * m2);
                float S = fmaf(s23, d01, s01 * d23);
                pr[r] = S * RCPF(d01 * d23);
            }
#pragma unroll
            for (int r = 0; r < 4; r++) DPP_REDUCE16(pr[r]);
            if (col == 0) {
                int rowbase = (g0 + gi) * 16 + q * 4;
#pragma unroll
                for (int r = 0; r < 4; r++)
                    out[(rowbase + r) * LATENT + lat] = pr[r] + b2v;
            }
        }
    }
}

// --- fp32 fallback (no workspace needed) ---
__global__ __launch_bounds__(256) void fallback_kernel(const float* __restrict__ u, const float* __restrict__ W1,
                                                       const float* __restrict__ b1, const float* __restrict__ W2,
                                                       const float* __restrict__ b2, float* __restrict__ out) {
    int idx = blockIdx.x * 256 + threadIdx.x;
    if (idx >= BATCH * LATENT) return;
    int b = idx >> 7;
    int lat = idx & 127;
    const float* ub = u + b * INDIM;
    float s = 0.0f;
    for (int h = 0; h < HIDDEN; h++) {
        const float* wp = W1 + (lat * HIDDEN + h) * INDIM;
        float dd = b1[lat * HIDDEN + h];
        for (int k = 0; k < INDIM; k++) dd += ub[k] * wp[k];
        s += tanhf(dd) * W2[lat * HIDDEN + h];
    }
    out[idx] = s + b2[lat];
}

extern "C" void kernel_launch(void* const* d_in, const int* in_sizes, int n_in,
                              void* d_out, int out_size, void* d_ws, size_t ws_size,
                              hipStream_t stream) {
    const float* u  = (const float*)d_in[0];
    const float* W1 = (const float*)d_in[1];
    const float* b1 = (const float*)d_in[2];
    const float* W2 = (const float*)d_in[3];
    const float* b2 = (const float*)d_in[4];
    float* out = (float*)d_out;

    const size_t UF_BYTES = (size_t)BATCH * KPAD * 2;           // 4 MiB
    const size_t WF_BYTES = (size_t)LATENT * HIDDEN * KPAD * 2; // 2 MiB

    if (ws_size < UF_BYTES + WF_BYTES) {
        fallback_kernel<<<(BATCH * LATENT + 255) / 256, 256, 0, stream>>>(u, W1, b1, W2, b2, out);
        return;
    }

    shortx8* uf = (shortx8*)d_ws;
    shortx8* wf = (shortx8*)((char*)d_ws + UF_BYTES);

    prep_transpose<<<384, 256, 0, stream>>>(u, W1, b1, uf, wf);
    branch_mlp<<<dim3(BATCH / 256, LATENT / 4), 256, 0, stream>>>(uf, wf, W2, b2, out);
}

// Round 5
// 124.739 us; speedup vs baseline: 1.1530x; 1.1530x over previous
//
#include <hip/hip_runtime.h>

#define BATCH 16384
#define LATENT 128
#define HIDDEN 64
#define INDIM 100
#define KPAD 128

typedef short shortx8 __attribute__((ext_vector_type(8)));
typedef float floatx4 __attribute__((ext_vector_type(4)));

__device__ __forceinline__ short f2bf(float f) {
    union { float f; unsigned u; } v; v.f = f;
    unsigned r = v.u + 0x7FFF + ((v.u >> 16) & 1);   // RNE, inputs finite
    return (short)(r >> 16);
}

#if __has_builtin(__builtin_amdgcn_exp2f)
#define EXP2F(x) __builtin_amdgcn_exp2f(x)
#else
#define EXP2F(x) __exp2f(x)
#endif
#if __has_builtin(__builtin_amdgcn_rcpf)
#define RCPF(x) __builtin_amdgcn_rcpf(x)
#else
#define RCPF(x) (1.0f / (x))
#endif

#define N_U_CHUNKS (BATCH * KPAD / 8)            // 262144
#define N_W_CHUNKS (LATENT * HIDDEN * KPAD / 8)  // 131072

// --- fused pre-pass (round-3 proven): bf16 fragment-major uf (ones col k=100)
// and wf (b1 at k=100) in one launch ---
__global__ __launch_bounds__(256) void prep_all(const float* __restrict__ u,
                                                const float* __restrict__ W1,
                                                const float* __restrict__ b1,
                                                shortx8* __restrict__ uf,
                                                shortx8* __restrict__ wf) {
    int c = blockIdx.x * 256 + threadIdx.x;
    if (c < N_U_CHUNKS) {
        int lane = c & 63;
        int kt = (c >> 6) & 3;
        int g = c >> 8;
        int row = g * 16 + (lane & 15);
        int kbase = kt * 32 + ((lane >> 4) << 3);
        shortx8 v;
        if (kbase + 7 < INDIM) {
            const float4* p = (const float4*)(u + row * INDIM + kbase);
            float4 f0 = p[0], f1 = p[1];
            v[0] = f2bf(f0.x); v[1] = f2bf(f0.y); v[2] = f2bf(f0.z); v[3] = f2bf(f0.w);
            v[4] = f2bf(f1.x); v[5] = f2bf(f1.y); v[6] = f2bf(f1.z); v[7] = f2bf(f1.w);
        } else {
#pragma unroll
            for (int j = 0; j < 8; j++) {
                int k = kbase + j;
                float f = (k < INDIM) ? u[row * INDIM + k] : (k == INDIM ? 1.0f : 0.0f);
                v[j] = f2bf(f);
            }
        }
        uf[c] = v;
    } else {
        int c2 = c - N_U_CHUNKS;
        int lane = c2 & 63;
        int kt = (c2 >> 6) & 3;
        int nt = (c2 >> 8) & 3;
        int lat = c2 >> 10;
        int h = nt * 16 + (lane & 15);
        int hw = lat * HIDDEN + h;
        int kbase = kt * 32 + ((lane >> 4) << 3);
        shortx8 v;
        if (kbase + 7 < INDIM) {
            const float4* p = (const float4*)(W1 + hw * INDIM + kbase);
            float4 f0 = p[0], f1 = p[1];
            v[0] = f2bf(f0.x); v[1] = f2bf(f0.y); v[2] = f2bf(f0.z); v[3] = f2bf(f0.w);
            v[4] = f2bf(f1.x); v[5] = f2bf(f1.y); v[6] = f2bf(f1.z); v[7] = f2bf(f1.w);
        } else {
#pragma unroll
            for (int j = 0; j < 8; j++) {
                int k = kbase + j;
                float f = (k < INDIM) ? W1[hw * INDIM + k] : (k == INDIM ? b1[hw] : 0.0f);
                v[j] = f2bf(f);
            }
        }
        wf[c2] = v;
    }
}

// ---------------------------------------------------------------------------
// main fused kernel — SWAPPED MFMA ORIENTATION.
// A-frag and B-frag share the same per-lane layout for 16x16x32, so feeding
// mfma(a=wf, b=uf) puts h on the output ROW axis (q*4+r, in-register) and
// batch on the COLUMN axis (lane&15). The h-reduction then folds into the
// per-lane tanh*W2 fma chain; only a 4-quad (stride-16 lane) butterfly
// remains: 2 shuffles per gi instead of round-3's 16 DPP mov+add pairs.
// grid (128, 32), 256 thr = 4 waves; wave = 32 batch rows (gi=2) x 4 latents.
// ---------------------------------------------------------------------------
__global__ __launch_bounds__(256, 4) void branch_mlp(const shortx8* __restrict__ uf,
                                                     const shortx8* __restrict__ wf,
                                                     const float* __restrict__ W2,
                                                     const float* __restrict__ b2,
                                                     float* __restrict__ out) {
    int tid = threadIdx.x;
    int lane = tid & 63;
    int w = tid >> 6;
    int bx = blockIdx.x;
    int by = blockIdx.y;
    int g0 = bx * 8 + w * 2;     // 16-row batch group base
    int q = lane >> 4;

    // uf fragments (now the B operand: columns = batch), wave-resident across li
    shortx8 ub[2][4];
    const shortx8* ua = uf + (size_t)g0 * 4 * 64 + lane;
#pragma unroll
    for (int gi = 0; gi < 2; gi++)
#pragma unroll
        for (int kt = 0; kt < 4; kt++)
            ub[gi][kt] = ua[(gi * 4 + kt) * 64];

#pragma unroll
    for (int li = 0; li < 4; li++) {
        int lat = by * 4 + li;
        const shortx8* wb = wf + (size_t)lat * 16 * 64 + lane;

        // W2 for this lane's 16 h-values (h = nt*16 + q*4 + r): 4x float4
        float4 w2v[4];
#pragma unroll
        for (int nt = 0; nt < 4; nt++)
            w2v[nt] = *(const float4*)(W2 + lat * HIDDEN + nt * 16 + q * 4);
        float b2v = b2[lat];

        // wf fragments (A operand: rows = h)
        shortx8 afr[4][4];
#pragma unroll
        for (int nt = 0; nt < 4; nt++)
#pragma unroll
            for (int kt = 0; kt < 4; kt++)
                afr[nt][kt] = wb[(nt * 4 + kt) * 64];

        floatx4 acc[2][4] = {};   // [gi][nt] ; D[row=h in nt-tile][col=batch in gi-tile]
#pragma unroll
        for (int kt = 0; kt < 4; kt++)
#pragma unroll
            for (int nt = 0; nt < 4; nt++)
#pragma unroll
                for (int gi = 0; gi < 2; gi++)
                    acc[gi][nt] = __builtin_amdgcn_mfma_f32_16x16x32_bf16(afr[nt][kt], ub[gi][kt], acc[gi][nt], 0, 0, 0);

        // epilogue: in-lane sum over this lane's 16 h of tanh(x)*W2[h],
        // then butterfly over the 4 quads (stride-16 lanes), store from lanes 0-15.
#pragma unroll
        for (int gi = 0; gi < 2; gi++) {
            float s = 0.0f;
#pragma unroll
            for (int nt = 0; nt < 4; nt++)
#pragma unroll
                for (int r = 0; r < 4; r++) {
                    float x = acc[gi][nt][r];
                    float e = EXP2F(x * 2.88539008177793f);   // exp(2x)
                    float rr = RCPF(e + 1.0f);
                    float t = fmaf(-2.0f, rr, 1.0f);          // tanh(x)
                    s = fmaf(t, w2v[nt][r], s);
                }
            s += __shfl_xor(s, 16, 64);
            s += __shfl_xor(s, 32, 64);
            if (lane < 16)
                out[((g0 + gi) * 16 + lane) * LATENT + lat] = s + b2v;
        }
    }
}

// --- fp32 fallback (no workspace needed) ---
__global__ __launch_bounds__(256) void fallback_kernel(const float* __restrict__ u, const float* __restrict__ W1,
                                                       const float* __restrict__ b1, const float* __restrict__ W2,
                                                       const float* __restrict__ b2, float* __restrict__ out) {
    int idx = blockIdx.x * 256 + threadIdx.x;
    if (idx >= BATCH * LATENT) return;
    int b = idx >> 7;
    int lat = idx & 127;
    const float* ub = u + b * INDIM;
    float s = 0.0f;
    for (int h = 0; h < HIDDEN; h++) {
        const float* wp = W1 + (lat * HIDDEN + h) * INDIM;
        float dd = b1[lat * HIDDEN + h];
        for (int k = 0; k < INDIM; k++) dd += ub[k] * wp[k];
        s += tanhf(dd) * W2[lat * HIDDEN + h];
    }
    out[idx] = s + b2[lat];
}

extern "C" void kernel_launch(void* const* d_in, const int* in_sizes, int n_in,
                              void* d_out, int out_size, void* d_ws, size_t ws_size,
                              hipStream_t stream) {
    const float* u  = (const float*)d_in[0];
    const float* W1 = (const float*)d_in[1];
    const float* b1 = (const float*)d_in[2];
    const float* W2 = (const float*)d_in[3];
    const float* b2 = (const float*)d_in[4];
    float* out = (float*)d_out;

    const size_t UF_BYTES = (size_t)BATCH * KPAD * 2;           // 4 MiB
    const size_t WF_BYTES = (size_t)LATENT * HIDDEN * KPAD * 2; // 2 MiB

    if (ws_size < UF_BYTES + WF_BYTES) {
        fallback_kernel<<<(BATCH * LATENT + 255) / 256, 256, 0, stream>>>(u, W1, b1, W2, b2, out);
        return;
    }

    shortx8* uf = (shortx8*)d_ws;
    shortx8* wf = (shortx8*)((char*)d_ws + UF_BYTES);

    prep_all<<<(N_U_CHUNKS + N_W_CHUNKS) / 256, 256, 0, stream>>>(u, W1, b1, uf, wf);
    branch_mlp<<<dim3(BATCH / 128, LATENT / 4), 256, 0, stream>>>(uf, wf, W2, b2, out);
}

// Round 6
// 112.841 us; speedup vs baseline: 1.2746x; 1.1054x over previous
//
#include <hip/hip_runtime.h>

#define BATCH 16384
#define LATENT 128
#define HIDDEN 64
#define INDIM 100
#define KPAD 128
#define TANH_SCALE 2.885390081777927f   // 2*log2(e): exp(2x) = exp2(SCALE*x)

typedef short shortx8 __attribute__((ext_vector_type(8)));
typedef float floatx4 __attribute__((ext_vector_type(4)));

__device__ __forceinline__ short f2bf(float f) {
    union { float f; unsigned u; } v; v.f = f;
    unsigned r = v.u + 0x7FFF + ((v.u >> 16) & 1);   // RNE, inputs finite
    return (short)(r >> 16);
}

#if __has_builtin(__builtin_amdgcn_exp2f)
#define EXP2F(x) __builtin_amdgcn_exp2f(x)
#else
#define EXP2F(x) __exp2f(x)
#endif
#if __has_builtin(__builtin_amdgcn_rcpf)
#define RCPF(x) __builtin_amdgcn_rcpf(x)
#else
#define RCPF(x) (1.0f / (x))
#endif

#define N_U_CHUNKS (BATCH * KPAD / 8)            // 262144
#define N_W_CHUNKS (LATENT * HIDDEN * KPAD / 8)  // 131072

// --- fused pre-pass: bf16 fragment-major uf (ones col k=100) and wf
// (b1 at k=100). W1/b1 pre-scaled by 2*log2(e) so the MFMA output feeds
// exp2 directly (saves one v_mul per tanh). Final block computes
// b2eff[lat] = b2[lat] + sum_h W2[lat][h]  (tanh = 1 - 2/(e+1) algebra). ---
__global__ __launch_bounds__(256) void prep_all(const float* __restrict__ u,
                                                const float* __restrict__ W1,
                                                const float* __restrict__ b1,
                                                const float* __restrict__ W2,
                                                const float* __restrict__ b2,
                                                shortx8* __restrict__ uf,
                                                shortx8* __restrict__ wf,
                                                float* __restrict__ b2eff) {
    int c = blockIdx.x * 256 + threadIdx.x;
    if (c < N_U_CHUNKS) {
        int lane = c & 63;
        int kt = (c >> 6) & 3;
        int g = c >> 8;
        int row = g * 16 + (lane & 15);
        int kbase = kt * 32 + ((lane >> 4) << 3);
        shortx8 v;
        if (kbase + 7 < INDIM) {
            const float4* p = (const float4*)(u + row * INDIM + kbase);
            float4 f0 = p[0], f1 = p[1];
            v[0] = f2bf(f0.x); v[1] = f2bf(f0.y); v[2] = f2bf(f0.z); v[3] = f2bf(f0.w);
            v[4] = f2bf(f1.x); v[5] = f2bf(f1.y); v[6] = f2bf(f1.z); v[7] = f2bf(f1.w);
        } else {
#pragma unroll
            for (int j = 0; j < 8; j++) {
                int k = kbase + j;
                float f = (k < INDIM) ? u[row * INDIM + k] : (k == INDIM ? 1.0f : 0.0f);
                v[j] = f2bf(f);
            }
        }
        uf[c] = v;
    } else if (c < N_U_CHUNKS + N_W_CHUNKS) {
        int c2 = c - N_U_CHUNKS;
        int lane = c2 & 63;
        int kt = (c2 >> 6) & 3;
        int nt = (c2 >> 8) & 3;
        int lat = c2 >> 10;
        int h = nt * 16 + (lane & 15);
        int hw = lat * HIDDEN + h;
        int kbase = kt * 32 + ((lane >> 4) << 3);
        shortx8 v;
        if (kbase + 7 < INDIM) {
            const float4* p = (const float4*)(W1 + hw * INDIM + kbase);
            float4 f0 = p[0], f1 = p[1];
            v[0] = f2bf(f0.x * TANH_SCALE); v[1] = f2bf(f0.y * TANH_SCALE);
            v[2] = f2bf(f0.z * TANH_SCALE); v[3] = f2bf(f0.w * TANH_SCALE);
            v[4] = f2bf(f1.x * TANH_SCALE); v[5] = f2bf(f1.y * TANH_SCALE);
            v[6] = f2bf(f1.z * TANH_SCALE); v[7] = f2bf(f1.w * TANH_SCALE);
        } else {
#pragma unroll
            for (int j = 0; j < 8; j++) {
                int k = kbase + j;
                float f = (k < INDIM) ? W1[hw * INDIM + k] * TANH_SCALE
                                      : (k == INDIM ? b1[hw] * TANH_SCALE : 0.0f);
                v[j] = f2bf(f);
            }
        }
        wf[c2] = v;
    } else {
        int lat = c - (N_U_CHUNKS + N_W_CHUNKS);
        if (lat < LATENT) {
            float s = b2[lat];
            const float* wp = W2 + lat * HIDDEN;
#pragma unroll 8
            for (int h = 0; h < HIDDEN; h++) s += wp[h];
            b2eff[lat] = s;
        }
    }
}

// ---------------------------------------------------------------------------
// Weight-stationary main kernel. Wave = ONE latent: afr[4][4] (full 16KB of
// that latent's W1 fragments, 64 regs) loads once; then 8 batch-groups of 16
// rows stream through (4 ub loads + 16 MFMAs + epilogue each). Cuts wf
// traffic 4x vs round 5 (1.07GB -> 268MB) and leaves only 4 in-flight loads
// per ~450-cyc iteration -> stalls vanish.
// Orientation (proven round 5): mfma(afr, ub) -> D row = h (nt*16+q*4+r),
// col = batch (lane&15). Epilogue per lane: s = sum_h -2*w2[h]/(exp2(y)+1);
// quad butterfly; b2eff (which carries sum_h w2) added at store.
// grid: 4096 blocks x 256 thr; block = 4 waves of the SAME latent (L1 reuse).
// ---------------------------------------------------------------------------
__global__ __launch_bounds__(256, 4) void branch_mlp(const shortx8* __restrict__ uf,
                                                     const shortx8* __restrict__ wf,
                                                     const float* __restrict__ W2,
                                                     const float* __restrict__ b2eff,
                                                     float* __restrict__ out) {
    int tid = threadIdx.x;
    int lane = tid & 63;
    int w = tid >> 6;
    int bx = blockIdx.x;
    int lat = bx >> 5;
    int G0 = (bx & 31) * 32 + w * 8;          // first of 8 batch 16-row groups
    int q = lane >> 4;

    // latent-resident weights: 16 fragment chunks (64 VGPRs)
    shortx8 afr[4][4];
    const shortx8* wb = wf + (size_t)lat * 16 * 64 + lane;
#pragma unroll
    for (int nt = 0; nt < 4; nt++)
#pragma unroll
        for (int kt = 0; kt < 4; kt++)
            afr[nt][kt] = wb[(nt * 4 + kt) * 64];

    // -2*W2 for this lane's 16 h-values (h = nt*16 + q*4 + r)
    float4 w2v[4];
#pragma unroll
    for (int nt = 0; nt < 4; nt++) {
        float4 t = *(const float4*)(W2 + lat * HIDDEN + nt * 16 + q * 4);
        w2v[nt] = make_float4(-2.0f * t.x, -2.0f * t.y, -2.0f * t.z, -2.0f * t.w);
    }
    float b2v = b2eff[lat];

    const shortx8* ua = uf + (size_t)G0 * 4 * 64 + lane;
    float* outp = out + (size_t)G0 * 16 * LATENT + lat;

#pragma unroll
    for (int g = 0; g < 8; g++) {
        shortx8 ub[4];
#pragma unroll
        for (int kt = 0; kt < 4; kt++)
            ub[kt] = ua[(g * 4 + kt) * 64];

        floatx4 acc[4] = {};   // [nt]: rows h, cols batch
#pragma unroll
        for (int kt = 0; kt < 4; kt++)
#pragma unroll
            for (int nt = 0; nt < 4; nt++)
                acc[nt] = __builtin_amdgcn_mfma_f32_16x16x32_bf16(afr[nt][kt], ub[kt], acc[nt], 0, 0, 0);

        float s = 0.0f;
#pragma unroll
        for (int nt = 0; nt < 4; nt++)
#pragma unroll
            for (int r = 0; r < 4; r++) {
                float e = EXP2F(acc[nt][r]);          // = exp(2x), scale folded into W1
                float rr = RCPF(e + 1.0f);
                s = fmaf((&w2v[nt].x)[r], rr, s);     // s += -2*w2*rr
            }
        s += __shfl_xor(s, 16, 64);
        s += __shfl_xor(s, 32, 64);
        if (lane < 16)
            outp[(g * 16 + lane) * LATENT] = s + b2v; // + b2 + sum_h w2
    }
}

// --- fp32 fallback (no workspace needed) ---
__global__ __launch_bounds__(256) void fallback_kernel(const float* __restrict__ u, const float* __restrict__ W1,
                                                       const float* __restrict__ b1, const float* __restrict__ W2,
                                                       const float* __restrict__ b2, float* __restrict__ out) {
    int idx = blockIdx.x * 256 + threadIdx.x;
    if (idx >= BATCH * LATENT) return;
    int b = idx >> 7;
    int lat = idx & 127;
    const float* ub = u + b * INDIM;
    float s = 0.0f;
    for (int h = 0; h < HIDDEN; h++) {
        const float* wp = W1 + (lat * HIDDEN + h) * INDIM;
        float dd = b1[lat * HIDDEN + h];
        for (int k = 0; k < INDIM; k++) dd += ub[k] * wp[k];
        s += tanhf(dd) * W2[lat * HIDDEN + h];
    }
    out[idx] = s + b2[lat];
}

extern "C" void kernel_launch(void* const* d_in, const int* in_sizes, int n_in,
                              void* d_out, int out_size, void* d_ws, size_t ws_size,
                              hipStream_t stream) {
    const float* u  = (const float*)d_in[0];
    const float* W1 = (const float*)d_in[1];
    const float* b1 = (const float*)d_in[2];
    const float* W2 = (const float*)d_in[3];
    const float* b2 = (const float*)d_in[4];
    float* out = (float*)d_out;

    const size_t UF_BYTES = (size_t)BATCH * KPAD * 2;           // 4 MiB
    const size_t WF_BYTES = (size_t)LATENT * HIDDEN * KPAD * 2; // 2 MiB
    const size_t B2_BYTES = LATENT * sizeof(float);

    if (ws_size < UF_BYTES + WF_BYTES + B2_BYTES) {
        fallback_kernel<<<(BATCH * LATENT + 255) / 256, 256, 0, stream>>>(u, W1, b1, W2, b2, out);
        return;
    }

    shortx8* uf = (shortx8*)d_ws;
    shortx8* wf = (shortx8*)((char*)d_ws + UF_BYTES);
    float* b2eff = (float*)((char*)d_ws + UF_BYTES + WF_BYTES);

    // 1536 blocks cover uf+wf chunks; +1 block computes b2eff
    prep_all<<<(N_U_CHUNKS + N_W_CHUNKS) / 256 + 1, 256, 0, stream>>>(u, W1, b1, W2, b2, uf, wf, b2eff);
    branch_mlp<<<4096, 256, 0, stream>>>(uf, wf, W2, b2eff, out);
}